// Round 7
// baseline (1582.292 us; speedup 1.0000x reference)
//
#include <hip/hip_runtime.h>

// Problem constants (from reference): T=512, N=1024, MC=512, H=5, M=20, NF=20
#define T_DIM 512
#define N_DIM 1024
#define MC_DIM 512
#define H_DIM 5
#define M_WIN 20
#define NF_DIM 20

typedef __attribute__((ext_vector_type(8))) short short8;
typedef __attribute__((ext_vector_type(4))) float f32x4;

__device__ __forceinline__ unsigned short f2bf(float f) {
  unsigned int u = __float_as_uint(f);
  u += 0x7fffu + ((u >> 16) & 1u);   // round-to-nearest-even
  return (unsigned short)(u >> 16);
}

// ---------------------------------------------------------------------------
// WW[t,i,n] = sum_k phi[k,i] * Wpad[t+k, n]  (bf16 out, layout [t][i][n])
// grid (N/256, T)
__global__ __launch_bounds__(256) void ww_kernel(const float* __restrict__ W,
                                                 const float* __restrict__ phi,
                                                 unsigned short* __restrict__ WWb) {
  __shared__ float phis[M_WIN * H_DIM];
  int tid = threadIdx.x;
  if (tid < M_WIN * H_DIM) phis[tid] = phi[tid];
  __syncthreads();
  int n = blockIdx.x * 256 + tid;
  int t = blockIdx.y;
  float acc[H_DIM] = {0.f, 0.f, 0.f, 0.f, 0.f};
  int k0 = 19 - t; if (k0 < 0) k0 = 0;
  for (int k = k0; k < M_WIN; ++k) {
    float wv = W[(t + k - 19) * N_DIM + n];
#pragma unroll
    for (int i = 0; i < H_DIM; ++i) acc[i] += phis[k * H_DIM + i] * wv;
  }
#pragma unroll
  for (int i = 0; i < H_DIM; ++i)
    WWb[(size_t)(t * H_DIM + i) * N_DIM + n] = f2bf(acc[i]);
}

// Esc[c,i,n] = sigma[i]^0.25 * E[c,n,i]   (bf16 out, layout [c][i][n])
// grid (N/256, MC)
__global__ __launch_bounds__(256) void esc_kernel(const float* __restrict__ E,
                                                  const float* __restrict__ sigma,
                                                  unsigned short* __restrict__ Escb) {
  int tid = threadIdx.x;
  int n = blockIdx.x * 256 + tid;
  int c = blockIdx.y;
#pragma unroll
  for (int i = 0; i < H_DIM; ++i) {
    float s4 = powf(sigma[i], 0.25f);
    float v = E[((size_t)c * N_DIM + n) * H_DIM + i] * s4;
    Escb[(size_t)(c * H_DIM + i) * N_DIM + n] = f2bf(v);
  }
}

// Et2[n][(f,c)] = E_stu[f,c,n]  fp32 (10240 x 1024) -> bf16 (1024 x 10240) transpose
// grid (10240/32, 1024/32), block 256 (32x8)
__global__ __launch_bounds__(256) void transpose_conv_kernel(const float* __restrict__ in,
                                                             unsigned short* __restrict__ out) {
  __shared__ float tile[32][33];
  int tx = threadIdx.x & 31, ty = threadIdx.x >> 5;
  int d0 = blockIdx.x * 32, n0 = blockIdx.y * 32;
#pragma unroll
  for (int k = 0; k < 4; ++k) {
    int r = ty + k * 8;
    tile[r][tx] = in[(size_t)(d0 + r) * N_DIM + n0 + tx];
  }
  __syncthreads();
#pragma unroll
  for (int k = 0; k < 4; ++k) {
    int r = ty + k * 8;
    out[(size_t)(n0 + r) * 10240 + d0 + tx] = f2bf(tile[tx][r]);
  }
}

// ---------------------------------------------------------------------------
// Generic C(MxN) = A(MxD) * B(NxD)^T, bf16 MFMA 16x16x32, 128x128 tile, BK=32.
// AF32/BF32: operand is fp32 in global, converted to bf16 during LDS staging.
// grid (N/128, M/128, split); kChunk = D/split (mult of 32).
// mode: 0 = plain store, 1 = atomicAdd(+v) (split-K), 2 = atomicAdd(-v).
template <bool AF32, bool BF32>
__global__ __launch_bounds__(256) void gemm_bt(const void* __restrict__ Ap,
                                               const void* __restrict__ Bp,
                                               float* __restrict__ C,
                                               int Ddim, int Ncols, int kChunk, int mode) {
  __shared__ unsigned short As[128 * 32];
  __shared__ unsigned short Bs[128 * 32];
  int tid = threadIdx.x;
  int lane = tid & 63, wave = tid >> 6;
  int wr = (wave >> 1) * 64, wc = (wave & 1) * 64;
  int m0 = blockIdx.y * 128, n0 = blockIdx.x * 128;
  int kBeg = blockIdx.z * kChunk, kEnd = kBeg + kChunk;
  int srow = tid >> 1, scol = (tid & 1) * 16;
  f32x4 zero = {0.f, 0.f, 0.f, 0.f};
  f32x4 acc[4][4];
#pragma unroll
  for (int i = 0; i < 4; ++i)
#pragma unroll
    for (int j = 0; j < 4; ++j) acc[i][j] = zero;

  int fr = lane & 15, fq = lane >> 4;

  for (int kk = kBeg; kk < kEnd; kk += 32) {
    // ---- stage A tile (rows m0.., cols kk..kk+31) ----
    if (AF32) {
      const float* A = (const float*)Ap;
      const float4* src = (const float4*)(A + (size_t)(m0 + srow) * Ddim + kk + scol);
      float4 v0 = src[0], v1 = src[1], v2 = src[2], v3 = src[3];
      float vals[16] = {v0.x, v0.y, v0.z, v0.w, v1.x, v1.y, v1.z, v1.w,
                        v2.x, v2.y, v2.z, v2.w, v3.x, v3.y, v3.z, v3.w};
      unsigned int pk[8];
#pragma unroll
      for (int e = 0; e < 8; ++e)
        pk[e] = (unsigned int)f2bf(vals[2 * e]) | ((unsigned int)f2bf(vals[2 * e + 1]) << 16);
      uint4* dst = (uint4*)&As[srow * 32 + scol];
      dst[0] = make_uint4(pk[0], pk[1], pk[2], pk[3]);
      dst[1] = make_uint4(pk[4], pk[5], pk[6], pk[7]);
    } else {
      const unsigned short* A = (const unsigned short*)Ap;
      const uint4* src = (const uint4*)(A + (size_t)(m0 + srow) * Ddim + kk + scol);
      uint4* dst = (uint4*)&As[srow * 32 + scol];
      dst[0] = src[0];
      dst[1] = src[1];
    }
    // ---- stage B tile (rows n0.., cols kk..kk+31) ----
    if (BF32) {
      const float* B = (const float*)Bp;
      const float4* src = (const float4*)(B + (size_t)(n0 + srow) * Ddim + kk + scol);
      float4 v0 = src[0], v1 = src[1], v2 = src[2], v3 = src[3];
      float vals[16] = {v0.x, v0.y, v0.z, v0.w, v1.x, v1.y, v1.z, v1.w,
                        v2.x, v2.y, v2.z, v2.w, v3.x, v3.y, v3.z, v3.w};
      unsigned int pk[8];
#pragma unroll
      for (int e = 0; e < 8; ++e)
        pk[e] = (unsigned int)f2bf(vals[2 * e]) | ((unsigned int)f2bf(vals[2 * e + 1]) << 16);
      uint4* dst = (uint4*)&Bs[srow * 32 + scol];
      dst[0] = make_uint4(pk[0], pk[1], pk[2], pk[3]);
      dst[1] = make_uint4(pk[4], pk[5], pk[6], pk[7]);
    } else {
      const unsigned short* B = (const unsigned short*)Bp;
      const uint4* src = (const uint4*)(B + (size_t)(n0 + srow) * Ddim + kk + scol);
      uint4* dst = (uint4*)&Bs[srow * 32 + scol];
      dst[0] = src[0];
      dst[1] = src[1];
    }
    __syncthreads();
    // ---- fragments + MFMA: A[m=lane&15][k=quad*8+j], C/D: col=lane&15, row=quad*4+reg ----
    short8 af[4], bf_[4];
#pragma unroll
    for (int i = 0; i < 4; ++i)
      af[i] = *(const short8*)&As[(wr + i * 16 + fr) * 32 + fq * 8];
#pragma unroll
    for (int j = 0; j < 4; ++j)
      bf_[j] = *(const short8*)&Bs[(wc + j * 16 + fr) * 32 + fq * 8];
#pragma unroll
    for (int i = 0; i < 4; ++i)
#pragma unroll
      for (int j = 0; j < 4; ++j)
        acc[i][j] = __builtin_amdgcn_mfma_f32_16x16x32_bf16(af[i], bf_[j], acc[i][j], 0, 0, 0);
    __syncthreads();
  }
  // ---- epilogue ----
#pragma unroll
  for (int i = 0; i < 4; ++i) {
#pragma unroll
    for (int j = 0; j < 4; ++j) {
      int mBase = m0 + wr + i * 16 + fq * 4;
      int nIdx = n0 + wc + j * 16 + fr;
#pragma unroll
      for (int r = 0; r < 4; ++r) {
        float v = acc[i][j][r];
        float* p = &C[(size_t)(mBase + r) * Ncols + nIdx];
        if (mode == 0) *p = v;
        else if (mode == 1) atomicAdd(p, v);
        else atomicAdd(p, -v);
      }
    }
  }
}

// ---------------------------------------------------------------------------
// R7: the 512-step feedback loop  u_t = p_t - y_t,  y_t = sum_f C_f (sum_{s<t}
// phi_stu[s,f] u_s)  is a strictly-causal linear fixed point  U = P - L(U).
// ||H_t||_2 ~ 2*sqrt(1024)*0.005*0.002*sqrt(512)*||phi_row|| ~ 0.003, so Jacobi
// U^{k+1} = P - L(U^k) converges superlinearly (error <= C(512,k)*0.003^k);
// 16 iterations covers a 2x norm misestimate. No fine-grained cross-block
// sync remains: each iteration = buildscan (phi-weighted exclusive prefix,
// bf16) + one 512x10240x512 MFMA GEMM subtracted into U via split-K atomics.

// Agg[t, f*512+c] = sum_{s<t} phi_stu[s,f] * U[s,c]   (bf16)   grid (40)
__global__ __launch_bounds__(256) void buildscan_kernel(const float* __restrict__ U,
                                                        const float* __restrict__ phi_stu,
                                                        unsigned short* __restrict__ Agg) {
  int j = blockIdx.x * 256 + threadIdx.x;   // 0..10239
  int f = j >> 9, c = j & 511;
  float acc = 0.f;
  for (int t = 0; t < T_DIM; ++t) {
    Agg[(size_t)t * 10240 + j] = f2bf(acc);
    acc += phi_stu[t * NF_DIM + f] * U[(size_t)t * MC_DIM + c];
  }
}

// Cb = bf16(Cmat), 512*10240 elems, 4 per thread, grid (5120)
__global__ __launch_bounds__(256) void cvt_kernel(const float* __restrict__ in,
                                                  unsigned short* __restrict__ out) {
  int i0 = (blockIdx.x * 256 + threadIdx.x) * 4;
#pragma unroll
  for (int e = 0; e < 4; ++e) out[i0 + e] = f2bf(in[i0 + e]);
}

// P[t,c] = upert[t,c] + bias[c], grid (1024)
__global__ __launch_bounds__(256) void padd_kernel(const float* __restrict__ upert,
                                                   const float* __restrict__ bias,
                                                   float* __restrict__ P) {
  int i = blockIdx.x * 256 + threadIdx.x;
  P[i] = upert[i] + bias[i & (MC_DIM - 1)];
}

// Rp[t][(f,c)] = phi_stu[t,f] * U[t,c]   (bf16)   grid (10240/256, T)
__global__ __launch_bounds__(256) void rp_kernel(const float* __restrict__ U,
                                                 const float* __restrict__ phi_stu,
                                                 unsigned short* __restrict__ Rp) {
  int t = blockIdx.y;
  int j = blockIdx.x * 256 + threadIdx.x;
  int f = j >> 9, c = j & 511;
  Rp[(size_t)t * 10240 + j] = f2bf(phi_stu[t * NF_DIM + f] * U[(size_t)t * MC_DIM + c]);
}

// ---- chunked exclusive prefix over t of G (T x N) -> X ----
__global__ __launch_bounds__(256) void scan1_kernel(const float* __restrict__ G, float* __restrict__ Psum) {
  int n = blockIdx.x * 256 + threadIdx.x;
  int c = blockIdx.y;
  float s = 0.f;
  for (int j = 0; j < 32; ++j) s += G[(size_t)(c * 32 + j) * N_DIM + n];
  Psum[c * N_DIM + n] = s;
}
__global__ __launch_bounds__(256) void scan2_kernel(float* __restrict__ Psum) {
  int n = blockIdx.x * 256 + threadIdx.x;
  float run = 0.f;
  for (int c = 0; c < 16; ++c) {
    float v = Psum[c * N_DIM + n];
    Psum[c * N_DIM + n] = run;
    run += v;
  }
}
__global__ __launch_bounds__(256) void scan3_kernel(const float* __restrict__ G, const float* __restrict__ Psum,
                                                    float* __restrict__ X) {
  int n = blockIdx.x * 256 + threadIdx.x;
  int c = blockIdx.y;
  float x = Psum[c * N_DIM + n];
  for (int j = 0; j < 32; ++j) {
    int t = c * 32 + j;
    X[(size_t)t * N_DIM + n] = x;
    x += G[(size_t)t * N_DIM + n];
  }
}

// losses[t] = dot(XQ[t], X[t]) + dot(UR[t], U[t])
__global__ __launch_bounds__(256) void loss_kernel(const float* __restrict__ XQ, const float* __restrict__ X,
                                                   const float* __restrict__ UR, const float* __restrict__ U,
                                                   float* __restrict__ out) {
  int t = blockIdx.x, tid = threadIdx.x;
  float s = 0.f;
  for (int j = tid; j < N_DIM; j += 256) s += XQ[(size_t)t * N_DIM + j] * X[(size_t)t * N_DIM + j];
  for (int c = tid; c < MC_DIM; c += 256) s += UR[(size_t)t * MC_DIM + c] * U[(size_t)t * MC_DIM + c];
#pragma unroll
  for (int off = 32; off > 0; off >>= 1) s += __shfl_down(s, off);
  __shared__ float red[4];
  if ((tid & 63) == 0) red[tid >> 6] = s;
  __syncthreads();
  if (tid == 0) out[t] = red[0] + red[1] + red[2] + red[3];
}

// ---------------------------------------------------------------------------
extern "C" void kernel_launch(void* const* d_in, const int* in_sizes, int n_in,
                              void* d_out, int out_size, void* d_ws, size_t ws_size,
                              hipStream_t stream) {
  const float* Q      = (const float*)d_in[0];
  const float* R      = (const float*)d_in[1];
  const float* Km     = (const float*)d_in[2];
  const float* E      = (const float*)d_in[3];
  const float* bias   = (const float*)d_in[4];
  const float* Estu   = (const float*)d_in[5];
  const float* phi    = (const float*)d_in[6];
  const float* sigma  = (const float*)d_in[7];
  const float* phistu = (const float*)d_in[8];
  const float* W      = (const float*)d_in[9];
  float* out = (float*)d_out;

  char* ws = (char*)d_ws;
  size_t off = 0;
  auto alloc = [&](size_t bytes) -> void* {
    void* p = ws + off;
    off += (bytes + 255) & ~(size_t)255;
    return p;
  };
  // split-K outputs (contiguous -> single memset)
  float* upert = (float*)alloc((size_t)512 * 512 * 4);    // 1 MB
  float* G     = (float*)alloc((size_t)512 * 1024 * 4);   // 2 MB
  float* XQ    = (float*)alloc((size_t)512 * 1024 * 4);   // 2 MB
  float* UR    = (float*)alloc((size_t)512 * 512 * 4);    // 1 MB
  float* Cmat  = (float*)alloc((size_t)512 * 10240 * 4);  // 20 MB
  float* X     = (float*)alloc((size_t)512 * 1024 * 4);   // 2 MB
  float* Psum  = (float*)alloc((size_t)16 * 1024 * 4);    // 64 KB
  float* Pbuf  = (float*)alloc((size_t)512 * 512 * 4);    // 1 MB
  float* Ua    = (float*)alloc((size_t)512 * 512 * 4);    // 1 MB
  float* Ub    = (float*)alloc((size_t)512 * 512 * 4);    // 1 MB
  unsigned short* Cb   = (unsigned short*)alloc((size_t)512 * 10240 * 2);  // 10 MB
  unsigned short* WWb  = (unsigned short*)alloc((size_t)512 * 5120 * 2);   // 5 MB
  unsigned short* Escb = (unsigned short*)alloc((size_t)512 * 5120 * 2);   // 5 MB
  unsigned short* Et2  = (unsigned short*)alloc((size_t)1024 * 10240 * 2); // 20 MB
  unsigned short* Agg  = WWb;  // alias: WWb+Escb (10 MB) dead after GEMM1
  unsigned short* Rp   = WWb;  // alias: Agg dead after the solve

  hipMemsetAsync(upert, 0, (size_t)6291456, stream);  // upert,G,XQ,UR (split-K accum)

  ww_kernel<<<dim3(4, 512), 256, 0, stream>>>(W, phi, WWb);
  esc_kernel<<<dim3(4, 512), 256, 0, stream>>>(E, sigma, Escb);
  transpose_conv_kernel<<<dim3(320, 32), 256, 0, stream>>>(Estu, Et2);

  // u_pert_raw(512x512) = WW(512x5120) * Esc(512x5120)^T   [split-K 8]
  gemm_bt<false, false><<<dim3(4, 4, 8), 256, 0, stream>>>(WWb, Escb, upert, 5120, 512, 640, 1);
  // Cmat(512x10240) = K(512x1024,f32) * Estu(10240x1024,f32)^T ; Cmat[c',f*512+c] = C_f[c',c]
  gemm_bt<true, true><<<dim3(80, 4, 1), 256, 0, stream>>>(Km, Estu, Cmat, 1024, 10240, 1024, 0);

  cvt_kernel<<<dim3(5120), 256, 0, stream>>>(Cmat, Cb);
  padd_kernel<<<dim3(1024), 256, 0, stream>>>(upert, bias, Pbuf);

  // ---- Jacobi solve of U = P - L(U), 16 iterations ----
  const float* Ucur = Pbuf;
  for (int k = 0; k < 16; ++k) {
    float* Unext = (k & 1) ? Ua : Ub;
    buildscan_kernel<<<dim3(40), 256, 0, stream>>>(Ucur, phistu, Agg);
    hipMemcpyAsync(Unext, Pbuf, (size_t)512 * 512 * 4, hipMemcpyDeviceToDevice, stream);
    // U_next = P - Agg(512x10240) * Cb(512x10240)^T   [split-K 16, negative atomics]
    gemm_bt<false, false><<<dim3(4, 4, 16), 256, 0, stream>>>(Agg, Cb, Unext, 10240, 512, 640, 2);
    Ucur = Unext;
  }
  const float* U = Ucur;   // final iterate (Ua after 16 iterations)

  // G(512x1024) = Rp(512x10240) * Et2(1024x10240)^T   [split-K 8]
  rp_kernel<<<dim3(40, 512), 256, 0, stream>>>(U, phistu, Rp);
  gemm_bt<false, false><<<dim3(8, 4, 8), 256, 0, stream>>>(Rp, Et2, G, 10240, 1024, 1280, 1);

  scan1_kernel<<<dim3(4, 16), 256, 0, stream>>>(G, Psum);
  scan2_kernel<<<dim3(4), 256, 0, stream>>>(Psum);
  scan3_kernel<<<dim3(4, 16), 256, 0, stream>>>(G, Psum, X);

  // XQ(512x1024) = X(512x1024,f32) * Q(1024x1024,f32)^T   [split-K 8]
  gemm_bt<true, true><<<dim3(8, 4, 8), 256, 0, stream>>>(X, Q, XQ, 1024, 1024, 128, 1);
  // UR(512x512)  = U(512x512,f32) * R(512x512,f32)^T      [split-K 8]
  gemm_bt<true, true><<<dim3(4, 4, 8), 256, 0, stream>>>(U, R, UR, 512, 512, 64, 1);

  loss_kernel<<<dim3(512), 256, 0, stream>>>(XQ, X, UR, U, out);
  (void)in_sizes; (void)n_in; (void)out_size; (void)ws_size;
}

// Round 8
// 940.326 us; speedup vs baseline: 1.6827x; 1.6827x over previous
//
#include <hip/hip_runtime.h>

// Problem constants (from reference): T=512, N=1024, MC=512, H=5, M=20, NF=20
#define T_DIM 512
#define N_DIM 1024
#define MC_DIM 512
#define H_DIM 5
#define M_WIN 20
#define NF_DIM 20

typedef __attribute__((ext_vector_type(8))) short short8;
typedef __attribute__((ext_vector_type(4))) float f32x4;

__device__ __forceinline__ unsigned short f2bf(float f) {
  unsigned int u = __float_as_uint(f);
  u += 0x7fffu + ((u >> 16) & 1u);   // round-to-nearest-even
  return (unsigned short)(u >> 16);
}

// ---------------------------------------------------------------------------
// WW[t,i,n] = sum_k phi[k,i] * Wpad[t+k, n]  (bf16 out, layout [t][i][n])
// grid (N/256, T)
__global__ __launch_bounds__(256) void ww_kernel(const float* __restrict__ W,
                                                 const float* __restrict__ phi,
                                                 unsigned short* __restrict__ WWb) {
  __shared__ float phis[M_WIN * H_DIM];
  int tid = threadIdx.x;
  if (tid < M_WIN * H_DIM) phis[tid] = phi[tid];
  __syncthreads();
  int n = blockIdx.x * 256 + tid;
  int t = blockIdx.y;
  float acc[H_DIM] = {0.f, 0.f, 0.f, 0.f, 0.f};
  int k0 = 19 - t; if (k0 < 0) k0 = 0;
  for (int k = k0; k < M_WIN; ++k) {
    float wv = W[(t + k - 19) * N_DIM + n];
#pragma unroll
    for (int i = 0; i < H_DIM; ++i) acc[i] += phis[k * H_DIM + i] * wv;
  }
#pragma unroll
  for (int i = 0; i < H_DIM; ++i)
    WWb[(size_t)(t * H_DIM + i) * N_DIM + n] = f2bf(acc[i]);
}

// Esc[c,i,n] = sigma[i]^0.25 * E[c,n,i]   (bf16 out, layout [c][i][n])
// grid (N/256, MC)
__global__ __launch_bounds__(256) void esc_kernel(const float* __restrict__ E,
                                                  const float* __restrict__ sigma,
                                                  unsigned short* __restrict__ Escb) {
  int tid = threadIdx.x;
  int n = blockIdx.x * 256 + tid;
  int c = blockIdx.y;
#pragma unroll
  for (int i = 0; i < H_DIM; ++i) {
    float s4 = powf(sigma[i], 0.25f);
    float v = E[((size_t)c * N_DIM + n) * H_DIM + i] * s4;
    Escb[(size_t)(c * H_DIM + i) * N_DIM + n] = f2bf(v);
  }
}

// Et2[n][(f,c)] = E_stu[f,c,n]  fp32 (10240 x 1024) -> bf16 (1024 x 10240) transpose
// grid (10240/32, 1024/32), block 256 (32x8)
__global__ __launch_bounds__(256) void transpose_conv_kernel(const float* __restrict__ in,
                                                             unsigned short* __restrict__ out) {
  __shared__ float tile[32][33];
  int tx = threadIdx.x & 31, ty = threadIdx.x >> 5;
  int d0 = blockIdx.x * 32, n0 = blockIdx.y * 32;
#pragma unroll
  for (int k = 0; k < 4; ++k) {
    int r = ty + k * 8;
    tile[r][tx] = in[(size_t)(d0 + r) * N_DIM + n0 + tx];
  }
  __syncthreads();
#pragma unroll
  for (int k = 0; k < 4; ++k) {
    int r = ty + k * 8;
    out[(size_t)(n0 + r) * 10240 + d0 + tx] = f2bf(tile[tx][r]);
  }
}

// ---------------------------------------------------------------------------
// Generic C(MxN) = A(MxD) * B(NxD)^T, bf16 MFMA 16x16x32, 128x128 tile, BK=32.
// AF32/BF32: operand is fp32 in global, converted to bf16 during LDS staging.
// grid (N/128, M/128, split); kChunk = D/split (mult of 32).
// mode: 0 = plain store, 1 = atomicAdd(+v) (split-K), 2 = atomicAdd(-v).
template <bool AF32, bool BF32>
__global__ __launch_bounds__(256) void gemm_bt(const void* __restrict__ Ap,
                                               const void* __restrict__ Bp,
                                               float* __restrict__ C,
                                               int Ddim, int Ncols, int kChunk, int mode) {
  __shared__ unsigned short As[128 * 32];
  __shared__ unsigned short Bs[128 * 32];
  int tid = threadIdx.x;
  int lane = tid & 63, wave = tid >> 6;
  int wr = (wave >> 1) * 64, wc = (wave & 1) * 64;
  int m0 = blockIdx.y * 128, n0 = blockIdx.x * 128;
  int kBeg = blockIdx.z * kChunk, kEnd = kBeg + kChunk;
  int srow = tid >> 1, scol = (tid & 1) * 16;
  f32x4 zero = {0.f, 0.f, 0.f, 0.f};
  f32x4 acc[4][4];
#pragma unroll
  for (int i = 0; i < 4; ++i)
#pragma unroll
    for (int j = 0; j < 4; ++j) acc[i][j] = zero;

  int fr = lane & 15, fq = lane >> 4;

  for (int kk = kBeg; kk < kEnd; kk += 32) {
    // ---- stage A tile (rows m0.., cols kk..kk+31) ----
    if (AF32) {
      const float* A = (const float*)Ap;
      const float4* src = (const float4*)(A + (size_t)(m0 + srow) * Ddim + kk + scol);
      float4 v0 = src[0], v1 = src[1], v2 = src[2], v3 = src[3];
      float vals[16] = {v0.x, v0.y, v0.z, v0.w, v1.x, v1.y, v1.z, v1.w,
                        v2.x, v2.y, v2.z, v2.w, v3.x, v3.y, v3.z, v3.w};
      unsigned int pk[8];
#pragma unroll
      for (int e = 0; e < 8; ++e)
        pk[e] = (unsigned int)f2bf(vals[2 * e]) | ((unsigned int)f2bf(vals[2 * e + 1]) << 16);
      uint4* dst = (uint4*)&As[srow * 32 + scol];
      dst[0] = make_uint4(pk[0], pk[1], pk[2], pk[3]);
      dst[1] = make_uint4(pk[4], pk[5], pk[6], pk[7]);
    } else {
      const unsigned short* A = (const unsigned short*)Ap;
      const uint4* src = (const uint4*)(A + (size_t)(m0 + srow) * Ddim + kk + scol);
      uint4* dst = (uint4*)&As[srow * 32 + scol];
      dst[0] = src[0];
      dst[1] = src[1];
    }
    // ---- stage B tile (rows n0.., cols kk..kk+31) ----
    if (BF32) {
      const float* B = (const float*)Bp;
      const float4* src = (const float4*)(B + (size_t)(n0 + srow) * Ddim + kk + scol);
      float4 v0 = src[0], v1 = src[1], v2 = src[2], v3 = src[3];
      float vals[16] = {v0.x, v0.y, v0.z, v0.w, v1.x, v1.y, v1.z, v1.w,
                        v2.x, v2.y, v2.z, v2.w, v3.x, v3.y, v3.z, v3.w};
      unsigned int pk[8];
#pragma unroll
      for (int e = 0; e < 8; ++e)
        pk[e] = (unsigned int)f2bf(vals[2 * e]) | ((unsigned int)f2bf(vals[2 * e + 1]) << 16);
      uint4* dst = (uint4*)&Bs[srow * 32 + scol];
      dst[0] = make_uint4(pk[0], pk[1], pk[2], pk[3]);
      dst[1] = make_uint4(pk[4], pk[5], pk[6], pk[7]);
    } else {
      const unsigned short* B = (const unsigned short*)Bp;
      const uint4* src = (const uint4*)(B + (size_t)(n0 + srow) * Ddim + kk + scol);
      uint4* dst = (uint4*)&Bs[srow * 32 + scol];
      dst[0] = src[0];
      dst[1] = src[1];
    }
    __syncthreads();
    // ---- fragments + MFMA: A[m=lane&15][k=quad*8+j], C/D: col=lane&15, row=quad*4+reg ----
    short8 af[4], bf_[4];
#pragma unroll
    for (int i = 0; i < 4; ++i)
      af[i] = *(const short8*)&As[(wr + i * 16 + fr) * 32 + fq * 8];
#pragma unroll
    for (int j = 0; j < 4; ++j)
      bf_[j] = *(const short8*)&Bs[(wc + j * 16 + fr) * 32 + fq * 8];
#pragma unroll
    for (int i = 0; i < 4; ++i)
#pragma unroll
      for (int j = 0; j < 4; ++j)
        acc[i][j] = __builtin_amdgcn_mfma_f32_16x16x32_bf16(af[i], bf_[j], acc[i][j], 0, 0, 0);
    __syncthreads();
  }
  // ---- epilogue ----
#pragma unroll
  for (int i = 0; i < 4; ++i) {
#pragma unroll
    for (int j = 0; j < 4; ++j) {
      int mBase = m0 + wr + i * 16 + fq * 4;
      int nIdx = n0 + wc + j * 16 + fr;
#pragma unroll
      for (int r = 0; r < 4; ++r) {
        float v = acc[i][j][r];
        float* p = &C[(size_t)(mBase + r) * Ncols + nIdx];
        if (mode == 0) *p = v;
        else if (mode == 1) atomicAdd(p, v);
        else atomicAdd(p, -v);
      }
    }
  }
}

// ---------------------------------------------------------------------------
// R8 Jacobi solve pieces: U = P - L(U), L strictly causal. 8 iterations.
// Per-iteration prefix scan is chunked (16 chunks of 32 steps) across 640
// blocks instead of 40 blocks x 512 serial steps.

// Tot[ch, j] = sum_{t in chunk ch} phi_stu[t,f] * U[t,c]   grid (40, 16)
__global__ __launch_bounds__(256) void chunksum_kernel(const float* __restrict__ U,
                                                       const float* __restrict__ phi_stu,
                                                       float* __restrict__ Tot) {
  int j = blockIdx.x * 256 + threadIdx.x;
  int ch = blockIdx.y;
  int f = j >> 9, c = j & 511;
  int t0 = ch * 32;
  float s = 0.f;
#pragma unroll 8
  for (int k = 0; k < 32; ++k) {
    int t = t0 + k;
    s += phi_stu[t * NF_DIM + f] * U[(size_t)t * MC_DIM + c];
  }
  Tot[ch * 10240 + j] = s;
}

// Agg[t, j] = bf16( sum_{ch'<ch} Tot[ch',j] + within-chunk exclusive prefix )
// grid (40, 16)
__global__ __launch_bounds__(256) void scanwrite_kernel(const float* __restrict__ U,
                                                        const float* __restrict__ phi_stu,
                                                        const float* __restrict__ Tot,
                                                        unsigned short* __restrict__ Agg) {
  int j = blockIdx.x * 256 + threadIdx.x;
  int ch = blockIdx.y;
  int f = j >> 9, c = j & 511;
  float acc = 0.f;
  for (int p = 0; p < ch; ++p) acc += Tot[p * 10240 + j];
  int t0 = ch * 32;
#pragma unroll 8
  for (int k = 0; k < 32; ++k) {
    int t = t0 + k;
    Agg[(size_t)t * 10240 + j] = f2bf(acc);
    acc += phi_stu[t * NF_DIM + f] * U[(size_t)t * MC_DIM + c];
  }
}

// Cb = bf16(Cmat), 512*10240 elems, 4 per thread, grid (5120)
__global__ __launch_bounds__(256) void cvt_kernel(const float* __restrict__ in,
                                                  unsigned short* __restrict__ out) {
  int i0 = (blockIdx.x * 256 + threadIdx.x) * 4;
#pragma unroll
  for (int e = 0; e < 4; ++e) out[i0 + e] = f2bf(in[i0 + e]);
}

// P[t,c] = upert[t,c] + bias[c], grid (1024)
__global__ __launch_bounds__(256) void padd_kernel(const float* __restrict__ upert,
                                                   const float* __restrict__ bias,
                                                   float* __restrict__ P) {
  int i = blockIdx.x * 256 + threadIdx.x;
  P[i] = upert[i] + bias[i & (MC_DIM - 1)];
}

// Rp[t][(f,c)] = phi_stu[t,f] * U[t,c]   (bf16)   grid (10240/256, T)
__global__ __launch_bounds__(256) void rp_kernel(const float* __restrict__ U,
                                                 const float* __restrict__ phi_stu,
                                                 unsigned short* __restrict__ Rp) {
  int t = blockIdx.y;
  int j = blockIdx.x * 256 + threadIdx.x;
  int f = j >> 9, c = j & 511;
  Rp[(size_t)t * 10240 + j] = f2bf(phi_stu[t * NF_DIM + f] * U[(size_t)t * MC_DIM + c]);
}

// ---- chunked exclusive prefix over t of G (T x N) -> X ----
__global__ __launch_bounds__(256) void scan1_kernel(const float* __restrict__ G, float* __restrict__ Psum) {
  int n = blockIdx.x * 256 + threadIdx.x;
  int c = blockIdx.y;
  float s = 0.f;
  for (int j = 0; j < 32; ++j) s += G[(size_t)(c * 32 + j) * N_DIM + n];
  Psum[c * N_DIM + n] = s;
}
__global__ __launch_bounds__(256) void scan2_kernel(float* __restrict__ Psum) {
  int n = blockIdx.x * 256 + threadIdx.x;
  float run = 0.f;
  for (int c = 0; c < 16; ++c) {
    float v = Psum[c * N_DIM + n];
    Psum[c * N_DIM + n] = run;
    run += v;
  }
}
__global__ __launch_bounds__(256) void scan3_kernel(const float* __restrict__ G, const float* __restrict__ Psum,
                                                    float* __restrict__ X) {
  int n = blockIdx.x * 256 + threadIdx.x;
  int c = blockIdx.y;
  float x = Psum[c * N_DIM + n];
  for (int j = 0; j < 32; ++j) {
    int t = c * 32 + j;
    X[(size_t)t * N_DIM + n] = x;
    x += G[(size_t)t * N_DIM + n];
  }
}

// losses[t] = dot(XQ[t], X[t]) + dot(UR[t], U[t])
__global__ __launch_bounds__(256) void loss_kernel(const float* __restrict__ XQ, const float* __restrict__ X,
                                                   const float* __restrict__ UR, const float* __restrict__ U,
                                                   float* __restrict__ out) {
  int t = blockIdx.x, tid = threadIdx.x;
  float s = 0.f;
  for (int j = tid; j < N_DIM; j += 256) s += XQ[(size_t)t * N_DIM + j] * X[(size_t)t * N_DIM + j];
  for (int c = tid; c < MC_DIM; c += 256) s += UR[(size_t)t * MC_DIM + c] * U[(size_t)t * MC_DIM + c];
#pragma unroll
  for (int off = 32; off > 0; off >>= 1) s += __shfl_down(s, off);
  __shared__ float red[4];
  if ((tid & 63) == 0) red[tid >> 6] = s;
  __syncthreads();
  if (tid == 0) out[t] = red[0] + red[1] + red[2] + red[3];
}

// ---------------------------------------------------------------------------
extern "C" void kernel_launch(void* const* d_in, const int* in_sizes, int n_in,
                              void* d_out, int out_size, void* d_ws, size_t ws_size,
                              hipStream_t stream) {
  const float* Q      = (const float*)d_in[0];
  const float* R      = (const float*)d_in[1];
  const float* Km     = (const float*)d_in[2];
  const float* E      = (const float*)d_in[3];
  const float* bias   = (const float*)d_in[4];
  const float* Estu   = (const float*)d_in[5];
  const float* phi    = (const float*)d_in[6];
  const float* sigma  = (const float*)d_in[7];
  const float* phistu = (const float*)d_in[8];
  const float* W      = (const float*)d_in[9];
  float* out = (float*)d_out;

  char* ws = (char*)d_ws;
  size_t off = 0;
  auto alloc = [&](size_t bytes) -> void* {
    void* p = ws + off;
    off += (bytes + 255) & ~(size_t)255;
    return p;
  };
  // split-K outputs (contiguous -> single memset)
  float* upert = (float*)alloc((size_t)512 * 512 * 4);    // 1 MB
  float* G     = (float*)alloc((size_t)512 * 1024 * 4);   // 2 MB
  float* XQ    = (float*)alloc((size_t)512 * 1024 * 4);   // 2 MB
  float* UR    = (float*)alloc((size_t)512 * 512 * 4);    // 1 MB
  float* Cmat  = (float*)alloc((size_t)512 * 10240 * 4);  // 20 MB
  float* X     = (float*)alloc((size_t)512 * 1024 * 4);   // 2 MB
  float* Psum  = (float*)alloc((size_t)16 * 1024 * 4);    // 64 KB
  float* Pbuf  = (float*)alloc((size_t)512 * 512 * 4);    // 1 MB
  float* Ua    = (float*)alloc((size_t)512 * 512 * 4);    // 1 MB
  float* Ub    = (float*)alloc((size_t)512 * 512 * 4);    // 1 MB
  float* Tot   = (float*)alloc((size_t)16 * 10240 * 4);   // 640 KB
  unsigned short* Cb   = (unsigned short*)alloc((size_t)512 * 10240 * 2);  // 10 MB
  unsigned short* WWb  = (unsigned short*)alloc((size_t)512 * 5120 * 2);   // 5 MB
  unsigned short* Escb = (unsigned short*)alloc((size_t)512 * 5120 * 2);   // 5 MB
  unsigned short* Et2  = (unsigned short*)alloc((size_t)1024 * 10240 * 2); // 20 MB
  unsigned short* Agg  = WWb;  // alias: WWb+Escb (10 MB) dead after GEMM1
  unsigned short* Rp   = WWb;  // alias: Agg dead after the solve

  hipMemsetAsync(upert, 0, (size_t)6291456, stream);  // upert,G,XQ,UR (split-K accum)

  ww_kernel<<<dim3(4, 512), 256, 0, stream>>>(W, phi, WWb);
  esc_kernel<<<dim3(4, 512), 256, 0, stream>>>(E, sigma, Escb);
  transpose_conv_kernel<<<dim3(320, 32), 256, 0, stream>>>(Estu, Et2);

  // u_pert_raw(512x512) = WW(512x5120) * Esc(512x5120)^T   [split-K 8]
  gemm_bt<false, false><<<dim3(4, 4, 8), 256, 0, stream>>>(WWb, Escb, upert, 5120, 512, 640, 1);
  // Cmat(512x10240) = K(512x1024,f32) * Estu(10240x1024,f32)^T ; Cmat[c',f*512+c] = C_f[c',c]
  gemm_bt<true, true><<<dim3(80, 4, 1), 256, 0, stream>>>(Km, Estu, Cmat, 1024, 10240, 1024, 0);

  cvt_kernel<<<dim3(5120), 256, 0, stream>>>(Cmat, Cb);
  padd_kernel<<<dim3(1024), 256, 0, stream>>>(upert, bias, Pbuf);

  // ---- Jacobi solve of U = P - L(U), 8 iterations ----
  const float* Ucur = Pbuf;
  for (int k = 0; k < 8; ++k) {
    float* Unext = (k & 1) ? Ua : Ub;
    chunksum_kernel<<<dim3(40, 16), 256, 0, stream>>>(Ucur, phistu, Tot);
    scanwrite_kernel<<<dim3(40, 16), 256, 0, stream>>>(Ucur, phistu, Tot, Agg);
    hipMemcpyAsync(Unext, Pbuf, (size_t)512 * 512 * 4, hipMemcpyDeviceToDevice, stream);
    // U_next = P - Agg(512x10240) * Cb(512x10240)^T   [split-K 64, negative atomics]
    gemm_bt<false, false><<<dim3(4, 4, 64), 256, 0, stream>>>(Agg, Cb, Unext, 10240, 512, 160, 2);
    Ucur = Unext;
  }
  const float* U = Ucur;   // final iterate

  // G(512x1024) = Rp(512x10240) * Et2(1024x10240)^T   [split-K 16]
  rp_kernel<<<dim3(40, 512), 256, 0, stream>>>(U, phistu, Rp);
  gemm_bt<false, false><<<dim3(8, 4, 16), 256, 0, stream>>>(Rp, Et2, G, 10240, 1024, 640, 1);

  scan1_kernel<<<dim3(4, 16), 256, 0, stream>>>(G, Psum);
  scan2_kernel<<<dim3(4), 256, 0, stream>>>(Psum);
  scan3_kernel<<<dim3(4, 16), 256, 0, stream>>>(G, Psum, X);

  // XQ(512x1024) = X(512x1024,f32) * Q(1024x1024,f32)^T   [split-K 8]
  gemm_bt<true, true><<<dim3(8, 4, 8), 256, 0, stream>>>(X, Q, XQ, 1024, 1024, 128, 1);
  // UR(512x512)  = U(512x512,f32) * R(512x512,f32)^T      [split-K 8]
  gemm_bt<true, true><<<dim3(4, 4, 8), 256, 0, stream>>>(U, R, UR, 512, 512, 64, 1);

  loss_kernel<<<dim3(512), 256, 0, stream>>>(XQ, X, UR, U, out);
  (void)in_sizes; (void)n_in; (void)out_size; (void)ws_size;
}

// Round 9
// 586.323 us; speedup vs baseline: 2.6987x; 1.6038x over previous
//
#include <hip/hip_runtime.h>

// Problem constants (from reference): T=512, N=1024, MC=512, H=5, M=20, NF=20
#define T_DIM 512
#define N_DIM 1024
#define MC_DIM 512
#define H_DIM 5
#define M_WIN 20
#define NF_DIM 20

typedef __attribute__((ext_vector_type(8))) short short8;
typedef __attribute__((ext_vector_type(4))) float f32x4;

__device__ __forceinline__ unsigned short f2bf(float f) {
  unsigned int u = __float_as_uint(f);
  u += 0x7fffu + ((u >> 16) & 1u);   // round-to-nearest-even
  return (unsigned short)(u >> 16);
}

// ---------------------------------------------------------------------------
// WW[t,i,n] = sum_k phi[k,i] * Wpad[t+k, n]  (bf16 out, layout [t][i][n])
// grid (N/256, T)
__global__ __launch_bounds__(256) void ww_kernel(const float* __restrict__ W,
                                                 const float* __restrict__ phi,
                                                 unsigned short* __restrict__ WWb) {
  __shared__ float phis[M_WIN * H_DIM];
  int tid = threadIdx.x;
  if (tid < M_WIN * H_DIM) phis[tid] = phi[tid];
  __syncthreads();
  int n = blockIdx.x * 256 + tid;
  int t = blockIdx.y;
  float acc[H_DIM] = {0.f, 0.f, 0.f, 0.f, 0.f};
  int k0 = 19 - t; if (k0 < 0) k0 = 0;
  for (int k = k0; k < M_WIN; ++k) {
    float wv = W[(t + k - 19) * N_DIM + n];
#pragma unroll
    for (int i = 0; i < H_DIM; ++i) acc[i] += phis[k * H_DIM + i] * wv;
  }
#pragma unroll
  for (int i = 0; i < H_DIM; ++i)
    WWb[(size_t)(t * H_DIM + i) * N_DIM + n] = f2bf(acc[i]);
}

// Esc[c,i,n] = sigma[i]^0.25 * E[c,n,i]   (bf16 out, layout [c][i][n])
// grid (N/256, MC)
__global__ __launch_bounds__(256) void esc_kernel(const float* __restrict__ E,
                                                  const float* __restrict__ sigma,
                                                  unsigned short* __restrict__ Escb) {
  int tid = threadIdx.x;
  int n = blockIdx.x * 256 + tid;
  int c = blockIdx.y;
#pragma unroll
  for (int i = 0; i < H_DIM; ++i) {
    float s4 = powf(sigma[i], 0.25f);
    float v = E[((size_t)c * N_DIM + n) * H_DIM + i] * s4;
    Escb[(size_t)(c * H_DIM + i) * N_DIM + n] = f2bf(v);
  }
}

// Et2[n][(f,c)] = E_stu[f,c,n]  fp32 (10240 x 1024) -> bf16 (1024 x 10240) transpose
// grid (10240/32, 1024/32), block 256 (32x8)
__global__ __launch_bounds__(256) void transpose_conv_kernel(const float* __restrict__ in,
                                                             unsigned short* __restrict__ out) {
  __shared__ float tile[32][33];
  int tx = threadIdx.x & 31, ty = threadIdx.x >> 5;
  int d0 = blockIdx.x * 32, n0 = blockIdx.y * 32;
#pragma unroll
  for (int k = 0; k < 4; ++k) {
    int r = ty + k * 8;
    tile[r][tx] = in[(size_t)(d0 + r) * N_DIM + n0 + tx];
  }
  __syncthreads();
#pragma unroll
  for (int k = 0; k < 4; ++k) {
    int r = ty + k * 8;
    out[(size_t)(n0 + r) * 10240 + d0 + tx] = f2bf(tile[tx][r]);
  }
}

// ---------------------------------------------------------------------------
// Generic C(MxN) = A(MxD) * B(NxD)^T, bf16 MFMA 16x16x32, 128x128 tile, BK=32.
// AF32/BF32: operand is fp32 in global, converted to bf16 during LDS staging.
// GRID ORDER (R9): x = K-split index (FASTEST -> XCD = kz%8, so each XCD's
// L2 only holds its own K-chunks of A and B: locality swizzle), y = N-tile,
// z = M-tile. kChunk = D/split (mult of 32).
// mode: 0 = plain store, 1 = atomicAdd(+v) (split-K), 2 = atomicAdd(-v).
template <bool AF32, bool BF32>
__global__ __launch_bounds__(256) void gemm_bt(const void* __restrict__ Ap,
                                               const void* __restrict__ Bp,
                                               float* __restrict__ C,
                                               int Ddim, int Ncols, int kChunk, int mode) {
  __shared__ unsigned short As[128 * 32];
  __shared__ unsigned short Bs[128 * 32];
  int tid = threadIdx.x;
  int lane = tid & 63, wave = tid >> 6;
  int wr = (wave >> 1) * 64, wc = (wave & 1) * 64;
  int m0 = blockIdx.z * 128, n0 = blockIdx.y * 128;
  int kBeg = blockIdx.x * kChunk, kEnd = kBeg + kChunk;
  int srow = tid >> 1, scol = (tid & 1) * 16;
  f32x4 zero = {0.f, 0.f, 0.f, 0.f};
  f32x4 acc[4][4];
#pragma unroll
  for (int i = 0; i < 4; ++i)
#pragma unroll
    for (int j = 0; j < 4; ++j) acc[i][j] = zero;

  int fr = lane & 15, fq = lane >> 4;

  for (int kk = kBeg; kk < kEnd; kk += 32) {
    // ---- stage A tile (rows m0.., cols kk..kk+31) ----
    if (AF32) {
      const float* A = (const float*)Ap;
      const float4* src = (const float4*)(A + (size_t)(m0 + srow) * Ddim + kk + scol);
      float4 v0 = src[0], v1 = src[1], v2 = src[2], v3 = src[3];
      float vals[16] = {v0.x, v0.y, v0.z, v0.w, v1.x, v1.y, v1.z, v1.w,
                        v2.x, v2.y, v2.z, v2.w, v3.x, v3.y, v3.z, v3.w};
      unsigned int pk[8];
#pragma unroll
      for (int e = 0; e < 8; ++e)
        pk[e] = (unsigned int)f2bf(vals[2 * e]) | ((unsigned int)f2bf(vals[2 * e + 1]) << 16);
      uint4* dst = (uint4*)&As[srow * 32 + scol];
      dst[0] = make_uint4(pk[0], pk[1], pk[2], pk[3]);
      dst[1] = make_uint4(pk[4], pk[5], pk[6], pk[7]);
    } else {
      const unsigned short* A = (const unsigned short*)Ap;
      const uint4* src = (const uint4*)(A + (size_t)(m0 + srow) * Ddim + kk + scol);
      uint4* dst = (uint4*)&As[srow * 32 + scol];
      dst[0] = src[0];
      dst[1] = src[1];
    }
    // ---- stage B tile (rows n0.., cols kk..kk+31) ----
    if (BF32) {
      const float* B = (const float*)Bp;
      const float4* src = (const float4*)(B + (size_t)(n0 + srow) * Ddim + kk + scol);
      float4 v0 = src[0], v1 = src[1], v2 = src[2], v3 = src[3];
      float vals[16] = {v0.x, v0.y, v0.z, v0.w, v1.x, v1.y, v1.z, v1.w,
                        v2.x, v2.y, v2.z, v2.w, v3.x, v3.y, v3.z, v3.w};
      unsigned int pk[8];
#pragma unroll
      for (int e = 0; e < 8; ++e)
        pk[e] = (unsigned int)f2bf(vals[2 * e]) | ((unsigned int)f2bf(vals[2 * e + 1]) << 16);
      uint4* dst = (uint4*)&Bs[srow * 32 + scol];
      dst[0] = make_uint4(pk[0], pk[1], pk[2], pk[3]);
      dst[1] = make_uint4(pk[4], pk[5], pk[6], pk[7]);
    } else {
      const unsigned short* B = (const unsigned short*)Bp;
      const uint4* src = (const uint4*)(B + (size_t)(n0 + srow) * Ddim + kk + scol);
      uint4* dst = (uint4*)&Bs[srow * 32 + scol];
      dst[0] = src[0];
      dst[1] = src[1];
    }
    __syncthreads();
    // ---- fragments + MFMA: A[m=lane&15][k=quad*8+j], C/D: col=lane&15, row=quad*4+reg ----
    short8 af[4], bf_[4];
#pragma unroll
    for (int i = 0; i < 4; ++i)
      af[i] = *(const short8*)&As[(wr + i * 16 + fr) * 32 + fq * 8];
#pragma unroll
    for (int j = 0; j < 4; ++j)
      bf_[j] = *(const short8*)&Bs[(wc + j * 16 + fr) * 32 + fq * 8];
#pragma unroll
    for (int i = 0; i < 4; ++i)
#pragma unroll
      for (int j = 0; j < 4; ++j)
        acc[i][j] = __builtin_amdgcn_mfma_f32_16x16x32_bf16(af[i], bf_[j], acc[i][j], 0, 0, 0);
    __syncthreads();
  }
  // ---- epilogue ----
#pragma unroll
  for (int i = 0; i < 4; ++i) {
#pragma unroll
    for (int j = 0; j < 4; ++j) {
      int mBase = m0 + wr + i * 16 + fq * 4;
      int nIdx = n0 + wc + j * 16 + fr;
#pragma unroll
      for (int r = 0; r < 4; ++r) {
        float v = acc[i][j][r];
        float* p = &C[(size_t)(mBase + r) * Ncols + nIdx];
        if (mode == 0) *p = v;
        else if (mode == 1) atomicAdd(p, v);
        else atomicAdd(p, -v);
      }
    }
  }
}

// ---------------------------------------------------------------------------
// R9 Jacobi solve pieces: U = P - L(U), L strictly causal. 5 iterations.
// Chunked prefix scan (16 chunks of 32 steps) across 640 blocks.

// Tot[ch, j] = sum_{t in chunk ch} phi_stu[t,f] * U[t,c]   grid (40, 16)
// Blocks with ch==0 additionally copy P -> Unext (folds the per-iteration
// D2D init into this launch).
__global__ __launch_bounds__(256) void chunksum_kernel(const float* __restrict__ U,
                                                       const float* __restrict__ phi_stu,
                                                       float* __restrict__ Tot,
                                                       const float* __restrict__ P,
                                                       float* __restrict__ Unext) {
  int j = blockIdx.x * 256 + threadIdx.x;
  int ch = blockIdx.y;
  int f = j >> 9, c = j & 511;
  int t0 = ch * 32;
  float s = 0.f;
#pragma unroll 8
  for (int k = 0; k < 32; ++k) {
    int t = t0 + k;
    s += phi_stu[t * NF_DIM + f] * U[(size_t)t * MC_DIM + c];
  }
  Tot[ch * 10240 + j] = s;
  if (ch == 0) {
#pragma unroll
    for (int r = 0; r < 26; ++r) {
      int idx = j + r * 10240;
      if (idx < T_DIM * MC_DIM) Unext[idx] = P[idx];
    }
  }
}

// Agg[t, j] = bf16( sum_{ch'<ch} Tot[ch',j] + within-chunk exclusive prefix )
// grid (40, 16)
__global__ __launch_bounds__(256) void scanwrite_kernel(const float* __restrict__ U,
                                                        const float* __restrict__ phi_stu,
                                                        const float* __restrict__ Tot,
                                                        unsigned short* __restrict__ Agg) {
  int j = blockIdx.x * 256 + threadIdx.x;
  int ch = blockIdx.y;
  int f = j >> 9, c = j & 511;
  float acc = 0.f;
  for (int p = 0; p < ch; ++p) acc += Tot[p * 10240 + j];
  int t0 = ch * 32;
#pragma unroll 8
  for (int k = 0; k < 32; ++k) {
    int t = t0 + k;
    Agg[(size_t)t * 10240 + j] = f2bf(acc);
    acc += phi_stu[t * NF_DIM + f] * U[(size_t)t * MC_DIM + c];
  }
}

// Cb = bf16(Cmat), 512*10240 elems, 4 per thread, grid (5120)
__global__ __launch_bounds__(256) void cvt_kernel(const float* __restrict__ in,
                                                  unsigned short* __restrict__ out) {
  int i0 = (blockIdx.x * 256 + threadIdx.x) * 4;
#pragma unroll
  for (int e = 0; e < 4; ++e) out[i0 + e] = f2bf(in[i0 + e]);
}

// P[t,c] = upert[t,c] + bias[c], grid (1024)
__global__ __launch_bounds__(256) void padd_kernel(const float* __restrict__ upert,
                                                   const float* __restrict__ bias,
                                                   float* __restrict__ P) {
  int i = blockIdx.x * 256 + threadIdx.x;
  P[i] = upert[i] + bias[i & (MC_DIM - 1)];
}

// Rp[t][(f,c)] = phi_stu[t,f] * U[t,c]   (bf16)   grid (10240/256, T)
__global__ __launch_bounds__(256) void rp_kernel(const float* __restrict__ U,
                                                 const float* __restrict__ phi_stu,
                                                 unsigned short* __restrict__ Rp) {
  int t = blockIdx.y;
  int j = blockIdx.x * 256 + threadIdx.x;
  int f = j >> 9, c = j & 511;
  Rp[(size_t)t * 10240 + j] = f2bf(phi_stu[t * NF_DIM + f] * U[(size_t)t * MC_DIM + c]);
}

// ---- chunked exclusive prefix over t of G (T x N) -> X ----
__global__ __launch_bounds__(256) void scan1_kernel(const float* __restrict__ G, float* __restrict__ Psum) {
  int n = blockIdx.x * 256 + threadIdx.x;
  int c = blockIdx.y;
  float s = 0.f;
  for (int j = 0; j < 32; ++j) s += G[(size_t)(c * 32 + j) * N_DIM + n];
  Psum[c * N_DIM + n] = s;
}
__global__ __launch_bounds__(256) void scan2_kernel(float* __restrict__ Psum) {
  int n = blockIdx.x * 256 + threadIdx.x;
  float run = 0.f;
  for (int c = 0; c < 16; ++c) {
    float v = Psum[c * N_DIM + n];
    Psum[c * N_DIM + n] = run;
    run += v;
  }
}
__global__ __launch_bounds__(256) void scan3_kernel(const float* __restrict__ G, const float* __restrict__ Psum,
                                                    float* __restrict__ X) {
  int n = blockIdx.x * 256 + threadIdx.x;
  int c = blockIdx.y;
  float x = Psum[c * N_DIM + n];
  for (int j = 0; j < 32; ++j) {
    int t = c * 32 + j;
    X[(size_t)t * N_DIM + n] = x;
    x += G[(size_t)t * N_DIM + n];
  }
}

// losses[t] = dot(XQ[t], X[t]) + dot(UR[t], U[t])
__global__ __launch_bounds__(256) void loss_kernel(const float* __restrict__ XQ, const float* __restrict__ X,
                                                   const float* __restrict__ UR, const float* __restrict__ U,
                                                   float* __restrict__ out) {
  int t = blockIdx.x, tid = threadIdx.x;
  float s = 0.f;
  for (int j = tid; j < N_DIM; j += 256) s += XQ[(size_t)t * N_DIM + j] * X[(size_t)t * N_DIM + j];
  for (int c = tid; c < MC_DIM; c += 256) s += UR[(size_t)t * MC_DIM + c] * U[(size_t)t * MC_DIM + c];
#pragma unroll
  for (int off = 32; off > 0; off >>= 1) s += __shfl_down(s, off);
  __shared__ float red[4];
  if ((tid & 63) == 0) red[tid >> 6] = s;
  __syncthreads();
  if (tid == 0) out[t] = red[0] + red[1] + red[2] + red[3];
}

// ---------------------------------------------------------------------------
extern "C" void kernel_launch(void* const* d_in, const int* in_sizes, int n_in,
                              void* d_out, int out_size, void* d_ws, size_t ws_size,
                              hipStream_t stream) {
  const float* Q      = (const float*)d_in[0];
  const float* R      = (const float*)d_in[1];
  const float* Km     = (const float*)d_in[2];
  const float* E      = (const float*)d_in[3];
  const float* bias   = (const float*)d_in[4];
  const float* Estu   = (const float*)d_in[5];
  const float* phi    = (const float*)d_in[6];
  const float* sigma  = (const float*)d_in[7];
  const float* phistu = (const float*)d_in[8];
  const float* W      = (const float*)d_in[9];
  float* out = (float*)d_out;

  char* ws = (char*)d_ws;
  size_t off = 0;
  auto alloc = [&](size_t bytes) -> void* {
    void* p = ws + off;
    off += (bytes + 255) & ~(size_t)255;
    return p;
  };
  // split-K outputs (contiguous -> single memset)
  float* upert = (float*)alloc((size_t)512 * 512 * 4);    // 1 MB
  float* G     = (float*)alloc((size_t)512 * 1024 * 4);   // 2 MB
  float* XQ    = (float*)alloc((size_t)512 * 1024 * 4);   // 2 MB
  float* UR    = (float*)alloc((size_t)512 * 512 * 4);    // 1 MB
  float* Cmat  = (float*)alloc((size_t)512 * 10240 * 4);  // 20 MB
  float* X     = (float*)alloc((size_t)512 * 1024 * 4);   // 2 MB
  float* Psum  = (float*)alloc((size_t)16 * 1024 * 4);    // 64 KB
  float* Pbuf  = (float*)alloc((size_t)512 * 512 * 4);    // 1 MB
  float* Ua    = (float*)alloc((size_t)512 * 512 * 4);    // 1 MB
  float* Ub    = (float*)alloc((size_t)512 * 512 * 4);    // 1 MB
  float* Tot   = (float*)alloc((size_t)16 * 10240 * 4);   // 640 KB
  unsigned short* Cb   = (unsigned short*)alloc((size_t)512 * 10240 * 2);  // 10 MB
  unsigned short* WWb  = (unsigned short*)alloc((size_t)512 * 5120 * 2);   // 5 MB
  unsigned short* Escb = (unsigned short*)alloc((size_t)512 * 5120 * 2);   // 5 MB
  unsigned short* Et2  = (unsigned short*)alloc((size_t)1024 * 10240 * 2); // 20 MB
  unsigned short* Agg  = WWb;  // alias: WWb+Escb (10 MB) dead after GEMM1
  unsigned short* Rp   = WWb;  // alias: Agg dead after the solve

  hipMemsetAsync(upert, 0, (size_t)6291456, stream);  // upert,G,XQ,UR (split-K accum)

  ww_kernel<<<dim3(4, 512), 256, 0, stream>>>(W, phi, WWb);
  esc_kernel<<<dim3(4, 512), 256, 0, stream>>>(E, sigma, Escb);
  transpose_conv_kernel<<<dim3(320, 32), 256, 0, stream>>>(Estu, Et2);

  // u_pert_raw(512x512) = WW(512x5120) * Esc(512x5120)^T   [split-K 8, k-fast]
  gemm_bt<false, false><<<dim3(8, 4, 4), 256, 0, stream>>>(WWb, Escb, upert, 5120, 512, 640, 1);
  // Cmat(512x10240) = K(512x1024,f32) * Estu(10240x1024,f32)^T ; Cmat[c',f*512+c] = C_f[c',c]
  gemm_bt<true, true><<<dim3(1, 80, 4), 256, 0, stream>>>(Km, Estu, Cmat, 1024, 10240, 1024, 0);

  cvt_kernel<<<dim3(5120), 256, 0, stream>>>(Cmat, Cb);
  padd_kernel<<<dim3(1024), 256, 0, stream>>>(upert, bias, Pbuf);

  // ---- Jacobi solve of U = P - L(U), 5 iterations ----
  const float* Ucur = Pbuf;
  for (int k = 0; k < 5; ++k) {
    float* Unext = (k & 1) ? Ua : Ub;
    chunksum_kernel<<<dim3(40, 16), 256, 0, stream>>>(Ucur, phistu, Tot, Pbuf, Unext);
    scanwrite_kernel<<<dim3(40, 16), 256, 0, stream>>>(Ucur, phistu, Tot, Agg);
    // U_next = P - Agg(512x10240) * Cb(512x10240)^T   [split-K 32, k-fast -> XCD-resident chunks]
    gemm_bt<false, false><<<dim3(32, 4, 4), 256, 0, stream>>>(Agg, Cb, Unext, 10240, 512, 320, 2);
    Ucur = Unext;
  }
  const float* U = Ucur;   // final iterate (Ub after 5 iterations)

  // G(512x1024) = Rp(512x10240) * Et2(1024x10240)^T   [split-K 16, k-fast]
  rp_kernel<<<dim3(40, 512), 256, 0, stream>>>(U, phistu, Rp);
  gemm_bt<false, false><<<dim3(16, 8, 4), 256, 0, stream>>>(Rp, Et2, G, 10240, 1024, 640, 1);

  scan1_kernel<<<dim3(4, 16), 256, 0, stream>>>(G, Psum);
  scan2_kernel<<<dim3(4), 256, 0, stream>>>(Psum);
  scan3_kernel<<<dim3(4, 16), 256, 0, stream>>>(G, Psum, X);

  // XQ(512x1024) = X(512x1024,f32) * Q(1024x1024,f32)^T   [split-K 8, k-fast]
  gemm_bt<true, true><<<dim3(8, 8, 4), 256, 0, stream>>>(X, Q, XQ, 1024, 1024, 128, 1);
  // UR(512x512)  = U(512x512,f32) * R(512x512,f32)^T      [split-K 8, k-fast]
  gemm_bt<true, true><<<dim3(8, 4, 4), 256, 0, stream>>>(U, R, UR, 512, 512, 64, 1);

  loss_kernel<<<dim3(512), 256, 0, stream>>>(XQ, X, UR, U, out);
  (void)in_sizes; (void)n_in; (void)out_size; (void)ws_size;
}